// Round 11
// baseline (295.839 us; speedup 1.0000x reference)
//
#include <hip/hip_runtime.h>

// ---------------------------------------------------------------------------
// MultiheadSparseReluAttention on MI355X (gfx950)
// Round 10 (resubmit; broker timeout): switch MFMA 16x16x32 -> 32x32x16 f16
// (m119: +20% matrix-pipe ceiling, half the MFMA instruction count, same LDS
// traffic). Schedule, swizzle, staging identical to the verified round-9
// kernel.
// ---------------------------------------------------------------------------

typedef _Float16 f16x8 __attribute__((ext_vector_type(8)));
typedef float f32x4 __attribute__((ext_vector_type(4)));
typedef float f32x16 __attribute__((ext_vector_type(16)));

#define L_DIM 2048
#define E_DIM 512
#define S_DIM 2048
#define SCALING_C 0.02209708691207961f   // 2048^-0.5

__device__ __forceinline__ int win_start(int l) {
    int local = l % 385;
    int blk   = l / 385;
    return ((blk & 1) == 0) ? (local << 2) : ((384 - local) << 2);
}

__device__ __forceinline__ void gload_lds16(const _Float16* g, _Float16* l) {
    __builtin_amdgcn_global_load_lds(
        (const __attribute__((address_space(1))) void*)g,
        (__attribute__((address_space(3))) void*)l, 16, 0, 0);
}

// ---------------------------------------------------------------------------
__global__ void cvt3(const float* __restrict__ p0, const float* __restrict__ p1,
                     const float* __restrict__ p2, _Float16* __restrict__ o0,
                     _Float16* __restrict__ o1, _Float16* __restrict__ o2,
                     int n0, int n1, int n2) {
    const int y = blockIdx.y;
    const float* in  = (y == 0) ? p0 : (y == 1) ? p1 : p2;
    _Float16*    out = (y == 0) ? o0 : (y == 1) ? o1 : o2;
    const int    n8  = (y == 0) ? n0 : (y == 1) ? n1 : n2;
    int i = blockIdx.x * 256 + threadIdx.x;
    if (i >= n8) return;
    const float4* p = (const float4*)in + 2 * (size_t)i;
    float4 a = p[0], b = p[1];
    f16x8 o = {(_Float16)a.x, (_Float16)a.y, (_Float16)a.z, (_Float16)a.w,
               (_Float16)b.x, (_Float16)b.y, (_Float16)b.z, (_Float16)b.w};
    *((f16x8*)out + i) = o;
}

// ---------------------------------------------------------------------------
__global__ void transpose_v(const _Float16* __restrict__ V,
                            _Float16* __restrict__ Vt) {
    __shared__ _Float16 t[32][33];
    int b  = blockIdx.z;
    int s0 = blockIdx.y * 32, e0 = blockIdx.x * 32;
    int tx = threadIdx.x & 31, ty = threadIdx.x >> 5;
    #pragma unroll
    for (int i = ty; i < 32; i += 8)
        t[i][tx] = V[((size_t)b * S_DIM + s0 + i) * E_DIM + e0 + tx];
    __syncthreads();
    #pragma unroll
    for (int i = ty; i < 32; i += 8)
        Vt[((size_t)b * E_DIM + e0 + i) * S_DIM + s0 + tx] = t[tx][i];
}

// ===========================================================================
// 256x256 tile, BK=64, 512 threads (8 waves 2Mx4N), dbuf LDS 128KB.
// 32x32x16 f16 MFMA. Wave tile 128x64 = 4 row-blocks x 2 col-blocks.
// One s_barrier + one vmcnt(0) per K-tile; A-frags pipelined one phase ahead.
// MODE 0: Q proj  MODE 1: K proj  MODE 3: attn
// ===========================================================================
#define STAGE256(b_, mat_, h_, j_) \
    gload_lds16(srcb[mat_] + (size_t)((h_) * 128 + (j_) * 8) * K, \
                &sm[b_][mat_][(h_) * 8192 + wid * 1024 + (j_) * 512])

template <int MODE>
__global__ __launch_bounds__(512, 2)
void gemm256(const _Float16* __restrict__ A, const _Float16* __restrict__ Bm,
             const float* __restrict__ bias, void* __restrict__ Cout,
             int K, size_t batchA, size_t batchB, int nbx, int nby) {
    __shared__ __align__(16) _Float16 sm[2][2][16384];   // [buf][A/B][256*64]

    const int nwg  = gridDim.x;
    const int orig = blockIdx.x;
    const int swz  = (orig & 7) * (nwg >> 3) + (orig >> 3);
    const int bx   = swz % nbx;
    const int rem  = swz / nbx;
    const int by   = rem % nby;
    const int z    = rem / nby;

    const int tid  = threadIdx.x;
    const int lane = tid & 63;
    const int wid  = tid >> 6;
    const int wr   = wid >> 2;          // M half (128 rows)
    const int wc   = wid & 3;           // N quarter (64 cols)
    const int row0 = by << 8, col0 = bx << 8;

    const _Float16* Ab = A + (size_t)z * batchA + (size_t)row0 * K;
    const _Float16* Bb = Bm + (size_t)z * batchB + (size_t)col0 * K;

    const int rl = wid * 16 + (lane >> 3);
    const int sc = ((lane & 7) ^ (lane >> 3)) << 3;
    const _Float16* srcb[2] = { Ab + (size_t)rl * K + sc,
                                Bb + (size_t)rl * K + sc };

    STAGE256(0, 0, 0, 0); STAGE256(0, 0, 0, 1); STAGE256(0, 0, 1, 0); STAGE256(0, 0, 1, 1);
    STAGE256(0, 1, 0, 0); STAGE256(0, 1, 0, 1); STAGE256(0, 1, 1, 0); STAGE256(0, 1, 1, 1);
    srcb[0] += 64; srcb[1] += 64;
    asm volatile("s_waitcnt vmcnt(0)" ::: "memory");
    __builtin_amdgcn_s_barrier();

    f32x16 acc[4][2] = {};
    const int l31 = lane & 31;
    const int hk  = lane >> 5;               // k-group half (0/1)
    // swizzled 16B-slot byte offsets for kk=0..3
    int sw[4];
    #pragma unroll
    for (int kk = 0; kk < 4; ++kk)
        sw[kk] = ((2 * kk + hk) ^ (lane & 7)) << 4;
    const int aoff = (wr * 128 + l31) * 128;   // byte base, A rows (+rb*4096)
    const int boff = (wc * 64 + l31) * 128;    // byte base, B rows (+cb*4096)
    const int NT   = K >> 6;

    for (int t = 0; t < NT; ++t) {
        const int  cur = t & 1, nxt = cur ^ 1;
        const bool pre = (t + 1 < NT);
        const char* bA = (const char*)&sm[cur][0][0];
        const char* bB = (const char*)&sm[cur][1][0];

        f16x8 bf[2][4], a[2][4];
        #pragma unroll
        for (int cb = 0; cb < 2; ++cb)
            #pragma unroll
            for (int kk = 0; kk < 4; ++kk)
                bf[cb][kk] = *(const f16x8*)(bB + boff + cb * 4096 + sw[kk]);
        #pragma unroll
        for (int kk = 0; kk < 4; ++kk)
            a[0][kk] = *(const f16x8*)(bA + aoff + 0 * 4096 + sw[kk]);
        if (pre) { STAGE256(nxt, 0, 0, 0); STAGE256(nxt, 0, 0, 1);
                   STAGE256(nxt, 0, 1, 0); STAGE256(nxt, 0, 1, 1); }

        #pragma unroll
        for (int p = 0; p < 4; ++p) {
            if (p < 3) {   // prefetch next row-block's A-frags
                #pragma unroll
                for (int kk = 0; kk < 4; ++kk)
                    a[(p + 1) & 1][kk] =
                        *(const f16x8*)(bA + aoff + (p + 1) * 4096 + sw[kk]);
            }
            if (p == 0 && pre) {
                STAGE256(nxt, 1, 0, 0); STAGE256(nxt, 1, 0, 1);
                STAGE256(nxt, 1, 1, 0); STAGE256(nxt, 1, 1, 1);
                srcb[0] += 64; srcb[1] += 64;
            }
            __builtin_amdgcn_s_setprio(1);
            #pragma unroll
            for (int kk = 0; kk < 4; ++kk)
                #pragma unroll
                for (int cb = 0; cb < 2; ++cb)
                    acc[p][cb] = __builtin_amdgcn_mfma_f32_32x32x16_f16(
                        a[p & 1][kk], bf[cb][kk], acc[p][cb], 0, 0, 0);
            __builtin_amdgcn_s_setprio(0);
        }
        asm volatile("s_waitcnt vmcnt(0)" ::: "memory");
        __builtin_amdgcn_s_barrier();
    }

    // epilogue: 32x32 C/D layout col=lane&31, row=(reg&3)+8*(reg>>2)+4*hk
    #pragma unroll
    for (int rb = 0; rb < 4; ++rb) {
        #pragma unroll
        for (int cb = 0; cb < 2; ++cb) {
            const int col = col0 + wc * 64 + cb * 32 + l31;
            float bvc = 0.f;
            if constexpr (MODE == 0 || MODE == 1) bvc = bias[col];
            #pragma unroll
            for (int reg = 0; reg < 16; ++reg) {
                const int row = row0 + wr * 128 + rb * 32 + hk * 4 +
                                (reg & 3) + 8 * (reg >> 2);
                float v = acc[rb][cb][reg];
                if constexpr (MODE == 0 || MODE == 1) {
                    v = fmaxf(v + bvc, 0.f);
                    if constexpr (MODE == 0) v *= SCALING_C;
                    const int l = row >> 2, bb = row & 3;
                    const int st = win_start(l);
                    if (col < st || col >= st + 512) v = 0.f;
                    ((_Float16*)Cout)[(((size_t)bb * L_DIM + l) << 11) + col] =
                        (_Float16)v;
                } else {  // MODE 3: attn f16 (b, L, S)
                    ((_Float16*)Cout)[(size_t)z * 4194304 +
                                      ((size_t)row << 11) + col] = (_Float16)v;
                }
            }
        }
    }
}

// ===========================================================================
// 128x128 tile, BK=64, 256 threads (4 waves 2x2), dbuf LDS 64KB (2 blk/CU).
// 32x32x16 f16 MFMA. Wave tile 64x64 = 2 row-blocks x 2 col-blocks.
// MODE 2: V proj  MODE 4: out GEMM
// ===========================================================================
#define STAGE128(b_, mat_, j_) \
    gload_lds16(srcb[mat_] + (size_t)((j_) * 32) * K, \
                &sm[b_][mat_][(j_) * 2048 + wid * 512])

template <int MODE>
__global__ __launch_bounds__(256, 2)
void gemm128p(const _Float16* __restrict__ A, const _Float16* __restrict__ Bm,
              const float* __restrict__ bias, void* __restrict__ Cout,
              int K, size_t batchA, size_t batchB, int nbx, int nby) {
    __shared__ __align__(16) _Float16 sm[2][2][8192];    // [buf][A/B][128*64]

    const int nwg  = gridDim.x;
    const int orig = blockIdx.x;
    const int swz  = (orig & 7) * (nwg >> 3) + (orig >> 3);
    const int bx   = swz % nbx;
    const int rem  = swz / nbx;
    const int by   = rem % nby;
    const int z    = rem / nby;

    const int tid  = threadIdx.x;
    const int lane = tid & 63;
    const int wid  = tid >> 6;
    const int wr   = wid >> 1;
    const int wc   = wid & 1;
    const int row0 = by << 7, col0 = bx << 7;

    const _Float16* Ab = A + (size_t)z * batchA + (size_t)row0 * K;
    const _Float16* Bb = Bm + (size_t)z * batchB + (size_t)col0 * K;

    const int rl = wid * 8 + (lane >> 3);
    const int sc = ((lane & 7) ^ (lane >> 3)) << 3;
    const _Float16* srcb[2] = { Ab + (size_t)rl * K + sc,
                                Bb + (size_t)rl * K + sc };

    STAGE128(0, 0, 0); STAGE128(0, 0, 1); STAGE128(0, 0, 2); STAGE128(0, 0, 3);
    STAGE128(0, 1, 0); STAGE128(0, 1, 1); STAGE128(0, 1, 2); STAGE128(0, 1, 3);
    srcb[0] += 64; srcb[1] += 64;
    asm volatile("s_waitcnt vmcnt(0)" ::: "memory");
    __builtin_amdgcn_s_barrier();

    f32x16 acc[2][2] = {};
    const int l31 = lane & 31;
    const int hk  = lane >> 5;
    int sw[4];
    #pragma unroll
    for (int kk = 0; kk < 4; ++kk)
        sw[kk] = ((2 * kk + hk) ^ (lane & 7)) << 4;
    const int aoff = (wr * 64 + l31) * 128;
    const int boff = (wc * 64 + l31) * 128;
    const int NT   = K >> 6;

    for (int t = 0; t < NT; ++t) {
        const int  cur = t & 1, nxt = cur ^ 1;
        const bool pre = (t + 1 < NT);
        const char* bA = (const char*)&sm[cur][0][0];
        const char* bB = (const char*)&sm[cur][1][0];

        f16x8 bf[2][4], a[2][4];
        #pragma unroll
        for (int cb = 0; cb < 2; ++cb)
            #pragma unroll
            for (int kk = 0; kk < 4; ++kk)
                bf[cb][kk] = *(const f16x8*)(bB + boff + cb * 4096 + sw[kk]);
        #pragma unroll
        for (int kk = 0; kk < 4; ++kk)
            a[0][kk] = *(const f16x8*)(bA + aoff + 0 * 4096 + sw[kk]);
        if (pre) { STAGE128(nxt, 0, 0); STAGE128(nxt, 0, 1);
                   STAGE128(nxt, 0, 2); STAGE128(nxt, 0, 3); }

        #pragma unroll
        for (int p = 0; p < 2; ++p) {
            if (p < 1) {
                #pragma unroll
                for (int kk = 0; kk < 4; ++kk)
                    a[1][kk] = *(const f16x8*)(bA + aoff + 1 * 4096 + sw[kk]);
            }
            if (p == 0 && pre) {
                STAGE128(nxt, 1, 0); STAGE128(nxt, 1, 1);
                STAGE128(nxt, 1, 2); STAGE128(nxt, 1, 3);
                srcb[0] += 64; srcb[1] += 64;
            }
            __builtin_amdgcn_s_setprio(1);
            #pragma unroll
            for (int kk = 0; kk < 4; ++kk)
                #pragma unroll
                for (int cb = 0; cb < 2; ++cb)
                    acc[p][cb] = __builtin_amdgcn_mfma_f32_32x32x16_f16(
                        a[p][kk], bf[cb][kk], acc[p][cb], 0, 0, 0);
            __builtin_amdgcn_s_setprio(0);
        }
        asm volatile("s_waitcnt vmcnt(0)" ::: "memory");
        __builtin_amdgcn_s_barrier();
    }

    #pragma unroll
    for (int rb = 0; rb < 2; ++rb) {
        #pragma unroll
        for (int cb = 0; cb < 2; ++cb) {
            const int col = col0 + wc * 64 + cb * 32 + l31;
            #pragma unroll
            for (int reg = 0; reg < 16; ++reg) {
                const int row = row0 + wr * 64 + rb * 32 + hk * 4 +
                                (reg & 3) + 8 * (reg >> 2);
                float v = acc[rb][cb][reg];
                if constexpr (MODE == 2) {
                    v += bias[col];
                    const int s = row >> 2, bb = row & 3;
                    ((_Float16*)Cout)[(((size_t)bb * S_DIM + s) << 9) + col] =
                        (_Float16)v;
                } else {  // MODE 4: out (L,B,E) fp32, row = l
                    ((float*)Cout)[(((size_t)row << 2) + z) * 512 + col] = v;
                }
            }
        }
    }
}

// ---------------------------------------------------------------------------
extern "C" void kernel_launch(void* const* d_in, const int* in_sizes, int n_in,
                              void* d_out, int out_size, void* d_ws,
                              size_t ws_size, hipStream_t stream) {
    const float* query = (const float*)d_in[0];
    const float* key_i = (const float*)d_in[1];
    const float* value = (const float*)d_in[2];
    const float* q_w   = (const float*)d_in[3];
    const float* q_b   = (const float*)d_in[4];
    const float* k_w   = (const float*)d_in[5];
    const float* k_b   = (const float*)d_in[6];
    const float* v_w   = (const float*)d_in[7];
    const float* v_b   = (const float*)d_in[8];

    _Float16* ws  = (_Float16*)d_ws;
    _Float16* qx  = ws;                    // 8192x512
    _Float16* kx  = qx + 4194304;
    _Float16* vx  = kx + 4194304;
    _Float16* qwf = vx + 4194304;          // 2048x512
    _Float16* kwf = qwf + 1048576;
    _Float16* vwf = kwf + 1048576;         // 512x512
    _Float16* Qb  = vwf + 262144;          // (B,L,D)
    _Float16* Kb  = Qb + 16777216;         // (B,S,D)
    _Float16* Vb  = Kb + 16777216;         // (B,S,E)
    _Float16* Vt  = Vb + 4194304;          // (B,E,S)
    _Float16* At  = Vt + 4194304;          // (B,L,S)

    cvt3<<<dim3(2048, 3), 256, 0, stream>>>(query, key_i, value, qx, kx, vx,
                                            524288, 524288, 524288);
    cvt3<<<dim3(512, 3), 256, 0, stream>>>(q_w, k_w, v_w, qwf, kwf, vwf,
                                           131072, 131072, 32768);

    gemm256<0><<<dim3(256), 512, 0, stream>>>(qx, qwf, q_b, Qb, 512, 0, 0, 8, 32);
    gemm256<1><<<dim3(256), 512, 0, stream>>>(kx, kwf, k_b, Kb, 512, 0, 0, 8, 32);
    gemm128p<2><<<dim3(256), 256, 0, stream>>>(vx, vwf, v_b, Vb, 512, 0, 0, 4, 64);

    transpose_v<<<dim3(16, 64, 4), 256, 0, stream>>>(Vb, Vt);

    gemm256<3><<<dim3(256), 512, 0, stream>>>(Qb, Kb, nullptr, At, 2048,
                                              4194304, 4194304, 8, 8);

    gemm128p<4><<<dim3(256), 256, 0, stream>>>(At, Vt, nullptr, d_out, 2048,
                                               4194304, 1048576, 4, 16);
}

// Round 12
// 288.497 us; speedup vs baseline: 1.0254x; 1.0254x over previous
//
#include <hip/hip_runtime.h>

// ---------------------------------------------------------------------------
// MultiheadSparseReluAttention on MI355X (gfx950)
// Round 12: fix the 32x32 LDS bank conflict (r11: 6.29M conflicts = +4cy per
// ds_read_b128). Storage swizzle enriched to f(r) = (r&7) ^ ((r>>3)&3) so
// conflict co-groups (lanes equal mod 8) read distinct slots. Schedule and
// everything else identical to round 10/11.
// ---------------------------------------------------------------------------

typedef _Float16 f16x8 __attribute__((ext_vector_type(8)));
typedef float f32x4 __attribute__((ext_vector_type(4)));
typedef float f32x16 __attribute__((ext_vector_type(16)));

#define L_DIM 2048
#define E_DIM 512
#define S_DIM 2048
#define SCALING_C 0.02209708691207961f   // 2048^-0.5

__device__ __forceinline__ int win_start(int l) {
    int local = l % 385;
    int blk   = l / 385;
    return ((blk & 1) == 0) ? (local << 2) : ((384 - local) << 2);
}

__device__ __forceinline__ void gload_lds16(const _Float16* g, _Float16* l) {
    __builtin_amdgcn_global_load_lds(
        (const __attribute__((address_space(1))) void*)g,
        (__attribute__((address_space(3))) void*)l, 16, 0, 0);
}

// ---------------------------------------------------------------------------
__global__ void cvt3(const float* __restrict__ p0, const float* __restrict__ p1,
                     const float* __restrict__ p2, _Float16* __restrict__ o0,
                     _Float16* __restrict__ o1, _Float16* __restrict__ o2,
                     int n0, int n1, int n2) {
    const int y = blockIdx.y;
    const float* in  = (y == 0) ? p0 : (y == 1) ? p1 : p2;
    _Float16*    out = (y == 0) ? o0 : (y == 1) ? o1 : o2;
    const int    n8  = (y == 0) ? n0 : (y == 1) ? n1 : n2;
    int i = blockIdx.x * 256 + threadIdx.x;
    if (i >= n8) return;
    const float4* p = (const float4*)in + 2 * (size_t)i;
    float4 a = p[0], b = p[1];
    f16x8 o = {(_Float16)a.x, (_Float16)a.y, (_Float16)a.z, (_Float16)a.w,
               (_Float16)b.x, (_Float16)b.y, (_Float16)b.z, (_Float16)b.w};
    *((f16x8*)out + i) = o;
}

// ---------------------------------------------------------------------------
__global__ void transpose_v(const _Float16* __restrict__ V,
                            _Float16* __restrict__ Vt) {
    __shared__ _Float16 t[32][33];
    int b  = blockIdx.z;
    int s0 = blockIdx.y * 32, e0 = blockIdx.x * 32;
    int tx = threadIdx.x & 31, ty = threadIdx.x >> 5;
    #pragma unroll
    for (int i = ty; i < 32; i += 8)
        t[i][tx] = V[((size_t)b * S_DIM + s0 + i) * E_DIM + e0 + tx];
    __syncthreads();
    #pragma unroll
    for (int i = ty; i < 32; i += 8)
        Vt[((size_t)b * E_DIM + e0 + i) * S_DIM + s0 + tx] = t[tx][i];
}

// ===========================================================================
// 256x256 tile, BK=64, 512 threads (8 waves 2Mx4N), dbuf LDS 128KB.
// 32x32x16 f16 MFMA. Swizzle f(r) = (r&7)^((r>>3)&3); storage col16 =
// (lane&7) ^ f(row); read slot = chunk ^ f(row).
// MODE 0: Q proj  MODE 1: K proj  MODE 3: attn
// ===========================================================================
#define STAGE256(b_, mat_, h_, j_) \
    gload_lds16(srcb[mat_] + (size_t)((h_) * 128 + (j_) * 8) * K + ((j_) ? sc1 : sc0), \
                &sm[b_][mat_][(h_) * 8192 + wid * 1024 + (j_) * 512])

template <int MODE>
__global__ __launch_bounds__(512, 2)
void gemm256(const _Float16* __restrict__ A, const _Float16* __restrict__ Bm,
             const float* __restrict__ bias, void* __restrict__ Cout,
             int K, size_t batchA, size_t batchB, int nbx, int nby) {
    __shared__ __align__(16) _Float16 sm[2][2][16384];   // [buf][A/B][256*64]

    const int nwg  = gridDim.x;
    const int orig = blockIdx.x;
    const int swz  = (orig & 7) * (nwg >> 3) + (orig >> 3);
    const int bx   = swz % nbx;
    const int rem  = swz / nbx;
    const int by   = rem % nby;
    const int z    = rem / nby;

    const int tid  = threadIdx.x;
    const int lane = tid & 63;
    const int wid  = tid >> 6;
    const int wr   = wid >> 2;          // M half (128 rows)
    const int wc   = wid & 3;           // N quarter (64 cols)
    const int row0 = by << 8, col0 = bx << 8;

    const _Float16* Ab = A + (size_t)z * batchA + (size_t)row0 * K;
    const _Float16* Bb = Bm + (size_t)z * batchB + (size_t)col0 * K;

    // staging: row r = h*128 + wid*16 + j*8 + (lane>>3); f(r) = (lane>>3) ^ ((2wid+j)&3)
    // global col16 = (lane&7) ^ f(r)
    const int rl  = wid * 16 + (lane >> 3);
    const int sc0 = (((lane & 7) ^ (lane >> 3) ^ ((2 * wid) & 3)) << 3);
    const int sc1 = (((lane & 7) ^ (lane >> 3) ^ ((2 * wid + 1) & 3)) << 3);
    const _Float16* srcb[2] = { Ab + (size_t)rl * K, Bb + (size_t)rl * K };

    STAGE256(0, 0, 0, 0); STAGE256(0, 0, 0, 1); STAGE256(0, 0, 1, 0); STAGE256(0, 0, 1, 1);
    STAGE256(0, 1, 0, 0); STAGE256(0, 1, 0, 1); STAGE256(0, 1, 1, 0); STAGE256(0, 1, 1, 1);
    srcb[0] += 64; srcb[1] += 64;
    asm volatile("s_waitcnt vmcnt(0)" ::: "memory");
    __builtin_amdgcn_s_barrier();

    f32x16 acc[4][2] = {};
    const int l31 = lane & 31;
    const int hk  = lane >> 5;               // k-group half (0/1)
    // read slot for logical chunk (2kk+hk): ^ (lane&7) ^ ((lane>>3)&3)
    int sw[4];
    #pragma unroll
    for (int kk = 0; kk < 4; ++kk)
        sw[kk] = (((2 * kk + hk) ^ (lane & 7) ^ ((lane >> 3) & 3)) << 4);
    const int aoff = (wr * 128 + l31) * 128;   // byte base, A rows (+rb*4096)
    const int boff = (wc * 64 + l31) * 128;    // byte base, B rows (+cb*4096)
    const int NT   = K >> 6;

    for (int t = 0; t < NT; ++t) {
        const int  cur = t & 1, nxt = cur ^ 1;
        const bool pre = (t + 1 < NT);
        const char* bA = (const char*)&sm[cur][0][0];
        const char* bB = (const char*)&sm[cur][1][0];

        f16x8 bf[2][4], a[2][4];
        #pragma unroll
        for (int cb = 0; cb < 2; ++cb)
            #pragma unroll
            for (int kk = 0; kk < 4; ++kk)
                bf[cb][kk] = *(const f16x8*)(bB + boff + cb * 4096 + sw[kk]);
        #pragma unroll
        for (int kk = 0; kk < 4; ++kk)
            a[0][kk] = *(const f16x8*)(bA + aoff + 0 * 4096 + sw[kk]);
        if (pre) { STAGE256(nxt, 0, 0, 0); STAGE256(nxt, 0, 0, 1);
                   STAGE256(nxt, 0, 1, 0); STAGE256(nxt, 0, 1, 1); }

        #pragma unroll
        for (int p = 0; p < 4; ++p) {
            if (p < 3) {   // prefetch next row-block's A-frags
                #pragma unroll
                for (int kk = 0; kk < 4; ++kk)
                    a[(p + 1) & 1][kk] =
                        *(const f16x8*)(bA + aoff + (p + 1) * 4096 + sw[kk]);
            }
            if (p == 0 && pre) {
                STAGE256(nxt, 1, 0, 0); STAGE256(nxt, 1, 0, 1);
                STAGE256(nxt, 1, 1, 0); STAGE256(nxt, 1, 1, 1);
                srcb[0] += 64; srcb[1] += 64;
            }
            __builtin_amdgcn_s_setprio(1);
            #pragma unroll
            for (int kk = 0; kk < 4; ++kk)
                #pragma unroll
                for (int cb = 0; cb < 2; ++cb)
                    acc[p][cb] = __builtin_amdgcn_mfma_f32_32x32x16_f16(
                        a[p & 1][kk], bf[cb][kk], acc[p][cb], 0, 0, 0);
            __builtin_amdgcn_s_setprio(0);
        }
        asm volatile("s_waitcnt vmcnt(0)" ::: "memory");
        __builtin_amdgcn_s_barrier();
    }

    // epilogue: 32x32 C/D layout col=lane&31, row=(reg&3)+8*(reg>>2)+4*hk
    #pragma unroll
    for (int rb = 0; rb < 4; ++rb) {
        #pragma unroll
        for (int cb = 0; cb < 2; ++cb) {
            const int col = col0 + wc * 64 + cb * 32 + l31;
            float bvc = 0.f;
            if constexpr (MODE == 0 || MODE == 1) bvc = bias[col];
            #pragma unroll
            for (int reg = 0; reg < 16; ++reg) {
                const int row = row0 + wr * 128 + rb * 32 + hk * 4 +
                                (reg & 3) + 8 * (reg >> 2);
                float v = acc[rb][cb][reg];
                if constexpr (MODE == 0 || MODE == 1) {
                    v = fmaxf(v + bvc, 0.f);
                    if constexpr (MODE == 0) v *= SCALING_C;
                    const int l = row >> 2, bb = row & 3;
                    const int st = win_start(l);
                    if (col < st || col >= st + 512) v = 0.f;
                    ((_Float16*)Cout)[(((size_t)bb * L_DIM + l) << 11) + col] =
                        (_Float16)v;
                } else {  // MODE 3: attn f16 (b, L, S)
                    ((_Float16*)Cout)[(size_t)z * 4194304 +
                                      ((size_t)row << 11) + col] = (_Float16)v;
                }
            }
        }
    }
}

// ===========================================================================
// 128x128 tile, BK=64, 256 threads (4 waves 2x2), dbuf LDS 64KB (2 blk/CU).
// 32x32x16 f16 MFMA, same enriched swizzle. MODE 2: V proj  MODE 4: out GEMM
// ===========================================================================
#define STAGE128(b_, mat_, j_) \
    gload_lds16(srcb[mat_] + (size_t)((j_) * 32) * K, \
                &sm[b_][mat_][(j_) * 2048 + wid * 512])

template <int MODE>
__global__ __launch_bounds__(256, 2)
void gemm128p(const _Float16* __restrict__ A, const _Float16* __restrict__ Bm,
              const float* __restrict__ bias, void* __restrict__ Cout,
              int K, size_t batchA, size_t batchB, int nbx, int nby) {
    __shared__ __align__(16) _Float16 sm[2][2][8192];    // [buf][A/B][128*64]

    const int nwg  = gridDim.x;
    const int orig = blockIdx.x;
    const int swz  = (orig & 7) * (nwg >> 3) + (orig >> 3);
    const int bx   = swz % nbx;
    const int rem  = swz / nbx;
    const int by   = rem % nby;
    const int z    = rem / nby;

    const int tid  = threadIdx.x;
    const int lane = tid & 63;
    const int wid  = tid >> 6;
    const int wr   = wid >> 1;
    const int wc   = wid & 1;
    const int row0 = by << 7, col0 = bx << 7;

    const _Float16* Ab = A + (size_t)z * batchA + (size_t)row0 * K;
    const _Float16* Bb = Bm + (size_t)z * batchB + (size_t)col0 * K;

    // staging: row r = j*32 + wid*8 + (lane>>3); f(r) = (lane>>3) ^ (wid&3)
    const int rl = wid * 8 + (lane >> 3);
    const int sc = (((lane & 7) ^ (lane >> 3) ^ (wid & 3)) << 3);
    const _Float16* srcb[2] = { Ab + (size_t)rl * K + sc,
                                Bb + (size_t)rl * K + sc };

    STAGE128(0, 0, 0); STAGE128(0, 0, 1); STAGE128(0, 0, 2); STAGE128(0, 0, 3);
    STAGE128(0, 1, 0); STAGE128(0, 1, 1); STAGE128(0, 1, 2); STAGE128(0, 1, 3);
    srcb[0] += 64; srcb[1] += 64;
    asm volatile("s_waitcnt vmcnt(0)" ::: "memory");
    __builtin_amdgcn_s_barrier();

    f32x16 acc[2][2] = {};
    const int l31 = lane & 31;
    const int hk  = lane >> 5;
    int sw[4];
    #pragma unroll
    for (int kk = 0; kk < 4; ++kk)
        sw[kk] = (((2 * kk + hk) ^ (lane & 7) ^ ((lane >> 3) & 3)) << 4);
    const int aoff = (wr * 64 + l31) * 128;
    const int boff = (wc * 64 + l31) * 128;
    const int NT   = K >> 6;

    for (int t = 0; t < NT; ++t) {
        const int  cur = t & 1, nxt = cur ^ 1;
        const bool pre = (t + 1 < NT);
        const char* bA = (const char*)&sm[cur][0][0];
        const char* bB = (const char*)&sm[cur][1][0];

        f16x8 bf[2][4], a[2][4];
        #pragma unroll
        for (int cb = 0; cb < 2; ++cb)
            #pragma unroll
            for (int kk = 0; kk < 4; ++kk)
                bf[cb][kk] = *(const f16x8*)(bB + boff + cb * 4096 + sw[kk]);
        #pragma unroll
        for (int kk = 0; kk < 4; ++kk)
            a[0][kk] = *(const f16x8*)(bA + aoff + 0 * 4096 + sw[kk]);
        if (pre) { STAGE128(nxt, 0, 0); STAGE128(nxt, 0, 1);
                   STAGE128(nxt, 0, 2); STAGE128(nxt, 0, 3); }

        #pragma unroll
        for (int p = 0; p < 2; ++p) {
            if (p < 1) {
                #pragma unroll
                for (int kk = 0; kk < 4; ++kk)
                    a[1][kk] = *(const f16x8*)(bA + aoff + 1 * 4096 + sw[kk]);
            }
            if (p == 0 && pre) {
                STAGE128(nxt, 1, 0); STAGE128(nxt, 1, 1);
                STAGE128(nxt, 1, 2); STAGE128(nxt, 1, 3);
                srcb[0] += 64; srcb[1] += 64;
            }
            __builtin_amdgcn_s_setprio(1);
            #pragma unroll
            for (int kk = 0; kk < 4; ++kk)
                #pragma unroll
                for (int cb = 0; cb < 2; ++cb)
                    acc[p][cb] = __builtin_amdgcn_mfma_f32_32x32x16_f16(
                        a[p][kk], bf[cb][kk], acc[p][cb], 0, 0, 0);
            __builtin_amdgcn_s_setprio(0);
        }
        asm volatile("s_waitcnt vmcnt(0)" ::: "memory");
        __builtin_amdgcn_s_barrier();
    }

    #pragma unroll
    for (int rb = 0; rb < 2; ++rb) {
        #pragma unroll
        for (int cb = 0; cb < 2; ++cb) {
            const int col = col0 + wc * 64 + cb * 32 + l31;
            #pragma unroll
            for (int reg = 0; reg < 16; ++reg) {
                const int row = row0 + wr * 64 + rb * 32 + hk * 4 +
                                (reg & 3) + 8 * (reg >> 2);
                float v = acc[rb][cb][reg];
                if constexpr (MODE == 2) {
                    v += bias[col];
                    const int s = row >> 2, bb = row & 3;
                    ((_Float16*)Cout)[(((size_t)bb * S_DIM + s) << 9) + col] =
                        (_Float16)v;
                } else {  // MODE 4: out (L,B,E) fp32, row = l
                    ((float*)Cout)[(((size_t)row << 2) + z) * 512 + col] = v;
                }
            }
        }
    }
}

// ---------------------------------------------------------------------------
extern "C" void kernel_launch(void* const* d_in, const int* in_sizes, int n_in,
                              void* d_out, int out_size, void* d_ws,
                              size_t ws_size, hipStream_t stream) {
    const float* query = (const float*)d_in[0];
    const float* key_i = (const float*)d_in[1];
    const float* value = (const float*)d_in[2];
    const float* q_w   = (const float*)d_in[3];
    const float* q_b   = (const float*)d_in[4];
    const float* k_w   = (const float*)d_in[5];
    const float* k_b   = (const float*)d_in[6];
    const float* v_w   = (const float*)d_in[7];
    const float* v_b   = (const float*)d_in[8];

    _Float16* ws  = (_Float16*)d_ws;
    _Float16* qx  = ws;                    // 8192x512
    _Float16* kx  = qx + 4194304;
    _Float16* vx  = kx + 4194304;
    _Float16* qwf = vx + 4194304;          // 2048x512
    _Float16* kwf = qwf + 1048576;
    _Float16* vwf = kwf + 1048576;         // 512x512
    _Float16* Qb  = vwf + 262144;          // (B,L,D)
    _Float16* Kb  = Qb + 16777216;         // (B,S,D)
    _Float16* Vb  = Kb + 16777216;         // (B,S,E)
    _Float16* Vt  = Vb + 4194304;          // (B,E,S)
    _Float16* At  = Vt + 4194304;          // (B,L,S)

    cvt3<<<dim3(2048, 3), 256, 0, stream>>>(query, key_i, value, qx, kx, vx,
                                            524288, 524288, 524288);
    cvt3<<<dim3(512, 3), 256, 0, stream>>>(q_w, k_w, v_w, qwf, kwf, vwf,
                                           131072, 131072, 32768);

    gemm256<0><<<dim3(256), 512, 0, stream>>>(qx, qwf, q_b, Qb, 512, 0, 0, 8, 32);
    gemm256<1><<<dim3(256), 512, 0, stream>>>(kx, kwf, k_b, Kb, 512, 0, 0, 8, 32);
    gemm128p<2><<<dim3(256), 256, 0, stream>>>(vx, vwf, v_b, Vb, 512, 0, 0, 4, 64);

    transpose_v<<<dim3(16, 64, 4), 256, 0, stream>>>(Vb, Vt);

    gemm256<3><<<dim3(256), 512, 0, stream>>>(Qb, Kb, nullptr, At, 2048,
                                              4194304, 4194304, 8, 8);

    gemm128p<4><<<dim3(256), 256, 0, stream>>>(At, Vt, nullptr, d_out, 2048,
                                               4194304, 1048576, 4, 16);
}